// Round 18
// baseline (249.856 us; speedup 1.0000x reference)
//
#include <hip/hip_runtime.h>

#define DEV static __device__ __forceinline__

typedef float f32x2 __attribute__((ext_vector_type(2)));

struct Cx { float r, i; };
DEV Cx cmul(Cx a, Cx b){ Cx o; o.r = a.r*b.r - a.i*b.i; o.i = a.r*b.i + a.i*b.r; return o; }

// ---- builtin DPP helpers (preamble / yx_pre only) ----
template<int CTRL>
DEV float dppf(float x){
  int v = __builtin_amdgcn_update_dpp(0, __builtin_bit_cast(int, x), CTRL, 0xF, 0xF, true);
  return __builtin_bit_cast(float, v);
}
DEV float rdl(float v, int l){
  return __builtin_bit_cast(float, __builtin_amdgcn_readlane(__builtin_bit_cast(int, v), l));
}
DEV float red64(float v){           // preamble-only (builtin form, proven R12)
  v += dppf<0x111>(v); v += dppf<0x112>(v); v += dppf<0x114>(v); v += dppf<0x118>(v);
  v += dppf<0x142>(v); v += dppf<0x143>(v);
  return rdl(v, 63);
}
DEV float sx16(float v){ return __shfl_xor(v, 16); }
DEV float sx32(float v){ return __shfl_xor(v, 32); }
DEV float full64(float v){
  v += dppf<0xB1>(v); v += dppf<0x4E>(v); v += dppf<0x124>(v); v += dppf<0x128>(v);
  v += sx16(v); v += sx32(v);
  return v;
}

// ---- fused-DPP asm blocks (interleaved chains; proven R15/R16/R17) ----
#define DPPMODS " row_mask:0xf bank_mask:0xf bound_ctrl:0\n\t"
DEV void red64x6_asm(float &a, float &b, float &c, float &d, float &e, float &f){
  asm("s_nop 1\n\t"
      "v_add_f32_dpp %0, %0, %0 quad_perm:[1,0,3,2]" DPPMODS
      "v_add_f32_dpp %1, %1, %1 quad_perm:[1,0,3,2]" DPPMODS
      "v_add_f32_dpp %2, %2, %2 quad_perm:[1,0,3,2]" DPPMODS
      "v_add_f32_dpp %3, %3, %3 quad_perm:[1,0,3,2]" DPPMODS
      "v_add_f32_dpp %4, %4, %4 quad_perm:[1,0,3,2]" DPPMODS
      "v_add_f32_dpp %5, %5, %5 quad_perm:[1,0,3,2]" DPPMODS
      "v_add_f32_dpp %0, %0, %0 quad_perm:[2,3,0,1]" DPPMODS
      "v_add_f32_dpp %1, %1, %1 quad_perm:[2,3,0,1]" DPPMODS
      "v_add_f32_dpp %2, %2, %2 quad_perm:[2,3,0,1]" DPPMODS
      "v_add_f32_dpp %3, %3, %3 quad_perm:[2,3,0,1]" DPPMODS
      "v_add_f32_dpp %4, %4, %4 quad_perm:[2,3,0,1]" DPPMODS
      "v_add_f32_dpp %5, %5, %5 quad_perm:[2,3,0,1]" DPPMODS
      "v_add_f32_dpp %0, %0, %0 row_ror:4" DPPMODS
      "v_add_f32_dpp %1, %1, %1 row_ror:4" DPPMODS
      "v_add_f32_dpp %2, %2, %2 row_ror:4" DPPMODS
      "v_add_f32_dpp %3, %3, %3 row_ror:4" DPPMODS
      "v_add_f32_dpp %4, %4, %4 row_ror:4" DPPMODS
      "v_add_f32_dpp %5, %5, %5 row_ror:4" DPPMODS
      "v_add_f32_dpp %0, %0, %0 row_ror:8" DPPMODS
      "v_add_f32_dpp %1, %1, %1 row_ror:8" DPPMODS
      "v_add_f32_dpp %2, %2, %2 row_ror:8" DPPMODS
      "v_add_f32_dpp %3, %3, %3 row_ror:8" DPPMODS
      "v_add_f32_dpp %4, %4, %4 row_ror:8" DPPMODS
      "v_add_f32_dpp %5, %5, %5 row_ror:8" DPPMODS
      "v_add_f32_dpp %0, %0, %0 row_bcast:15" DPPMODS
      "v_add_f32_dpp %1, %1, %1 row_bcast:15" DPPMODS
      "v_add_f32_dpp %2, %2, %2 row_bcast:15" DPPMODS
      "v_add_f32_dpp %3, %3, %3 row_bcast:15" DPPMODS
      "v_add_f32_dpp %4, %4, %4 row_bcast:15" DPPMODS
      "v_add_f32_dpp %5, %5, %5 row_bcast:15" DPPMODS
      "v_add_f32_dpp %0, %0, %0 row_bcast:31" DPPMODS
      "v_add_f32_dpp %1, %1, %1 row_bcast:31" DPPMODS
      "v_add_f32_dpp %2, %2, %2 row_bcast:31" DPPMODS
      "v_add_f32_dpp %3, %3, %3 row_bcast:31" DPPMODS
      "v_add_f32_dpp %4, %4, %4 row_bcast:31" DPPMODS
      "v_add_f32_dpp %5, %5, %5 row_bcast:31" DPPMODS
      : "+v"(a), "+v"(b), "+v"(c), "+v"(d), "+v"(e), "+v"(f));
}
DEV void zred_asm(float &A, float &B, float &C, float &D, float &E,
                  float rsg2, float rsg3){
  asm("s_nop 1\n\t"
      "v_add_f32_dpp %0, %0, %0 quad_perm:[1,0,3,2]" DPPMODS
      "v_add_f32_dpp %1, %1, %1 quad_perm:[1,0,3,2]" DPPMODS
      "v_add_f32_dpp %2, %2, %2 quad_perm:[1,0,3,2]" DPPMODS
      "v_add_f32_dpp %0, %0, %0 quad_perm:[2,3,0,1]" DPPMODS
      "v_add_f32_dpp %1, %1, %1 quad_perm:[2,3,0,1]" DPPMODS
      "v_add_f32_dpp %2, %2, %2 quad_perm:[2,3,0,1]" DPPMODS
      "v_mul_f32 %3, %5, %2\n\t"
      "v_mul_f32 %4, %6, %2\n\t"
      "v_add_f32_dpp %0, %0, %0 row_bcast:15" DPPMODS
      "v_add_f32_dpp %1, %1, %1 row_bcast:15" DPPMODS
      "v_add_f32_dpp %3, %3, %3 row_bcast:15" DPPMODS
      "v_add_f32_dpp %4, %4, %4 row_bcast:15" DPPMODS
      "v_add_f32_dpp %0, %0, %0 row_bcast:31" DPPMODS
      "v_add_f32_dpp %1, %1, %1 row_bcast:31" DPPMODS
      "v_add_f32_dpp %3, %3, %3 row_bcast:31" DPPMODS
      "v_add_f32_dpp %4, %4, %4 row_bcast:31" DPPMODS
      : "+v"(A), "+v"(B), "+v"(C), "=&v"(D), "=&v"(E)
      : "v"(rsg2), "v"(rsg3));
}
DEV void chunk2_asm(float &F, float &G){
  asm("s_nop 1\n\t"
      "v_add_f32_dpp %0, %0, %0 row_ror:4" DPPMODS
      "v_add_f32_dpp %1, %1, %1 row_ror:4" DPPMODS
      "s_nop 0\n\t"
      "v_add_f32_dpp %0, %0, %0 row_ror:8" DPPMODS
      "v_add_f32_dpp %1, %1, %1 row_ror:8" DPPMODS
      : "+v"(F), "+v"(G));
}
DEV void quadbcast12_asm(float a, float br, float bi,
  float &a0,float &a1,float &a2,float &a3,
  float &r0,float &r1,float &r2,float &r3,
  float &i0,float &i1,float &i2,float &i3){
  asm("s_nop 1\n\t"
      "v_mov_b32_dpp %0, %12 quad_perm:[0,0,0,0]" DPPMODS
      "v_mov_b32_dpp %1, %12 quad_perm:[1,1,1,1]" DPPMODS
      "v_mov_b32_dpp %2, %12 quad_perm:[2,2,2,2]" DPPMODS
      "v_mov_b32_dpp %3, %12 quad_perm:[3,3,3,3]" DPPMODS
      "v_mov_b32_dpp %4, %13 quad_perm:[0,0,0,0]" DPPMODS
      "v_mov_b32_dpp %5, %13 quad_perm:[1,1,1,1]" DPPMODS
      "v_mov_b32_dpp %6, %13 quad_perm:[2,2,2,2]" DPPMODS
      "v_mov_b32_dpp %7, %13 quad_perm:[3,3,3,3]" DPPMODS
      "v_mov_b32_dpp %8, %14 quad_perm:[0,0,0,0]" DPPMODS
      "v_mov_b32_dpp %9, %14 quad_perm:[1,1,1,1]" DPPMODS
      "v_mov_b32_dpp %10, %14 quad_perm:[2,2,2,2]" DPPMODS
      "v_mov_b32_dpp %11, %14 quad_perm:[3,3,3,3]" DPPMODS
      : "=&v"(a0), "=&v"(a1), "=&v"(a2), "=&v"(a3),
        "=&v"(r0), "=&v"(r1), "=&v"(r2), "=&v"(r3),
        "=&v"(i0), "=&v"(i1), "=&v"(i2), "=&v"(i3)
      : "v"(a), "v"(br), "v"(bi));
}

// ---- R18: packed-f32 asm blocks ----
// G = M0p (x) B0r-splat + sum_{m=1..3} (Mr_m + i Mi_m) * B_m, all as [re,im] pairs.
// cross term: lo: -Mi*Bi + Gr (op_sel S1 hi, neg_lo S0); hi: Mi*Br + Gi (op_sel_hi S1 lo).
DEV void gmatvec_pk(f32x2 &G, f32x2 M0p, f32x2 Mr1, f32x2 Mi1, f32x2 Mr2, f32x2 Mi2,
                    f32x2 Mr3, f32x2 Mi3, f32x2 B0, f32x2 B1, f32x2 B2, f32x2 B3){
  asm("v_pk_mul_f32 %0, %1, %8 op_sel_hi:[1,0]\n\t"
      "v_pk_fma_f32 %0, %2, %9, %0\n\t"
      "v_pk_fma_f32 %0, %3, %9, %0 op_sel:[0,1,0] op_sel_hi:[1,0,1] neg_lo:[1,0,0]\n\t"
      "v_pk_fma_f32 %0, %4, %10, %0\n\t"
      "v_pk_fma_f32 %0, %5, %10, %0 op_sel:[0,1,0] op_sel_hi:[1,0,1] neg_lo:[1,0,0]\n\t"
      "v_pk_fma_f32 %0, %6, %11, %0\n\t"
      "v_pk_fma_f32 %0, %7, %11, %0 op_sel:[0,1,0] op_sel_hi:[1,0,1] neg_lo:[1,0,0]\n\t"
      : "=&v"(G)
      : "v"(M0p), "v"(Mr1), "v"(Mi1), "v"(Mr2), "v"(Mi2), "v"(Mr3), "v"(Mi3),
        "v"(B0), "v"(B1), "v"(B2), "v"(B3));
}
// [og,oi] = GOb + sum_q [WgP_q,WiP_q]*z_q with z-broadcast via op_sel on Z pairs.
DEV void gates_pk(f32x2 &GO, f32x2 W0, f32x2 W1, f32x2 W2, f32x2 W3,
                  f32x2 Z01, f32x2 Z23, f32x2 GOb){
  asm("v_pk_fma_f32 %0, %1, %5, %7 op_sel_hi:[1,0,1]\n\t"
      "v_pk_fma_f32 %0, %2, %5, %0 op_sel:[0,1,0]\n\t"
      "v_pk_fma_f32 %0, %3, %6, %0 op_sel_hi:[1,0,1]\n\t"
      "v_pk_fma_f32 %0, %4, %6, %0 op_sel:[0,1,0]\n\t"
      : "=&v"(GO)
      : "v"(W0), "v"(W1), "v"(W2), "v"(W3), "v"(Z01), "v"(Z23), "v"(GOb));
}

DEV float fexp(float x){ return __builtin_amdgcn_exp2f(x * 1.44269504088896341f); }
DEV float ex2(float x){ return __builtin_amdgcn_exp2f(x); }
DEV float frcp(float x){ return __builtin_amdgcn_rcpf(x); }
DEV float frsq(float x){ return __builtin_amdgcn_rsqf(x); }
DEV float fsqrt_(float x){ return __builtin_amdgcn_sqrtf(x); }
DEV float med3(float x, float lo, float hi){ return __builtin_amdgcn_fmed3f(x, lo, hi); }

#define LOG2E 1.44269504088896341f

// =================== Kernel 1: Yx precompute + C2 bias fold [R17-proven] ===================
__global__ void yx_pre(const float* __restrict__ x, const float* __restrict__ fw,
                       const float* __restrict__ ew, const float* __restrict__ eb,
                       const float* __restrict__ nrb,
                       float* __restrict__ yx, long long nrows)
{
  const int lane = threadIdx.x & 63;
  const long long wid = (long long)blockIdx.x * (blockDim.x >> 6) + (threadIdx.x >> 6);
  const long long nw  = (long long)gridDim.x * (blockDim.x >> 6);
  float w0_,w1_,w2_,w3_,v0_,v1_,v2_,v3_;
  {
    const float f0 = fexp(fw[2*lane]), f1 = fexp(fw[2*lane+1]);
    w0_ = ew[0*192+2*lane]*f0; v0_ = ew[0*192+2*lane+1]*f1;
    w1_ = ew[1*192+2*lane]*f0; v1_ = ew[1*192+2*lane+1]*f1;
    w2_ = ew[2*192+2*lane]*f0; v2_ = ew[2*192+2*lane+1]*f1;
    w3_ = ew[3*192+2*lane]*f0; v3_ = ew[3*192+2*lane+1]*f1;
  }
  const float lb = nrb[lane];
  float b0,b1,b2,b3;
  {
    b0 = eb[0] + full64(ew[0*192+128+lane]*lb);
    b1 = eb[1] + full64(ew[1*192+128+lane]*lb);
    b2 = eb[2] + full64(ew[2*192+128+lane]*lb);
    b3 = eb[3] + full64(ew[3*192+128+lane]*lb);
  }
  for (long long row = wid; row < nrows; row += nw){
    const float2 xv = *(const float2*)(x + row*128 + 2*lane);
    float a0 = fmaf(v0_,xv.y, w0_*xv.x);
    float a1 = fmaf(v1_,xv.y, w1_*xv.x);
    float a2 = fmaf(v2_,xv.y, w2_*xv.x);
    float a3 = fmaf(v3_,xv.y, w3_*xv.x);
    a0 = full64(a0); a1 = full64(a1); a2 = full64(a2); a3 = full64(a3);
    if (lane == 0){
      float4 o; o.x=a0+b0; o.y=a1+b1; o.z=a2+b2; o.w=a3+b3;
      *(float4*)(yx + row*4) = o;
    }
  }
}

// =================== Kernel 2: recurrence, 64 lanes per element ===================
// R18 = R17 + packed-f32 G-matvec and og/oi gate matvec; hot loop unrolled x4.
__global__ void __launch_bounds__(64) qssm64(
  const float* __restrict__ ew, const float* __restrict__ exw,
  const float* __restrict__ exb,const float* __restrict__ vw,
  const float* __restrict__ nrw,const float* __restrict__ nrb,
  const float* __restrict__ yx, float* __restrict__ out,
  int T, long long hToff)
{
  const int lane = threadIdx.x;      // 0..63
  const int e    = blockIdx.x;       // batch element
  const int r    = lane >> 4;        // row
  const int m4   = lane & 3;         // quad position (qubit this lane encodes)
  const int k    = 4*m4 + r;         // amplitude this lane owns (F-matvec)
  const int c    = (lane >> 2) & 3;  // j-chunk this lane sums

  // ---------- build fixed circuit matrix M (16x16 complex) once [R4-verbatim] ----------
  __shared__ float MrS[16][16];
  __shared__ float MiS[16][16];
  if (lane < 16){
    const int j = lane;
    float w2[2][3][4];
    #pragma unroll
    for (int ll=0;ll<2;ll++)
      #pragma unroll
      for (int g=0;g<3;g++)
        #pragma unroll
        for (int i=0;i<4;i++) w2[ll][g][i] = 0.5f * vw[(ll*3+g)*4+i];
    float sr[16], si[16];
    #pragma unroll
    for (int n=0;n<16;n++){ sr[n] = (n==j)?1.f:0.f; si[n]=0.f; }
    #pragma unroll
    for (int ll=0;ll<2;ll++){
      #pragma unroll
      for (int cq=0;cq<4;cq++){
        const int tq=(cq+1)&3, mc=1<<(3-cq), mt=1<<(3-tq);
        #pragma unroll
        for (int n=0;n<16;n++){
          if ((n&mc) && !(n&mt)){
            const int n1 = n|mt;
            float tr=sr[n], ti=si[n];
            sr[n]=sr[n1]; si[n]=si[n1];
            sr[n1]=tr;    si[n1]=ti;
          }
        }
      }
      #pragma unroll
      for (int i=0;i<4;i++){
        const int m=1<<(3-i);
        const float cx=cosf(w2[ll][0][i]), sxx=sinf(w2[ll][0][i]);
        const float cy=cosf(w2[ll][1][i]), sy=sinf(w2[ll][1][i]);
        const float cz=cosf(w2[ll][2][i]), sz=sinf(w2[ll][2][i]);
        #pragma unroll
        for (int n=0;n<16;n++){
          if (!(n&m)){
            const int n1=n|m;
            float a0r=sr[n], a0i=si[n], a1r=sr[n1], a1i=si[n1];
            float b0r = cx*a0r + sxx*a1i, b0i = cx*a0i - sxx*a1r;
            float b1r = sxx*a0i + cx*a1r, b1i = -sxx*a0r + cx*a1i;
            float c0r = cy*b0r - sy*b1r, c0i = cy*b0i - sy*b1i;
            float c1r = sy*b0r + cy*b1r, c1i = sy*b0i + cy*b1i;
            sr[n]  = cz*c0r + sz*c0i;  si[n]  = cz*c0i - sz*c0r;
            sr[n1] = cz*c1r - sz*c1i;  si[n1] = cz*c1i + sz*c1r;
          }
        }
      }
    }
    #pragma unroll
    for (int n=0;n<16;n++){ MrS[n][j]=sr[n]; MiS[n][j]=si[n]; }
  }
  __syncthreads();

  // M fragment: row k, columns 4c..4c+3, as loop-invariant pairs for pk ops
  float Mr[4], Mi[4];
  #pragma unroll
  for (int m=0;m<4;m++){ Mr[m]=MrS[k][4*c+m]; Mi[m]=MiS[k][4*c+m]; }
  f32x2 M0p;  M0p.x = Mr[0]; M0p.y = Mi[0];
  f32x2 Mr1p; Mr1p.x = Mr[1]; Mr1p.y = Mr[1];
  f32x2 Mi1p; Mi1p.x = Mi[1]; Mi1p.y = Mi[1];
  f32x2 Mr2p; Mr2p.x = Mr[2]; Mr2p.y = Mr[2];
  f32x2 Mi2p; Mi2p.x = Mi[2]; Mi2p.y = Mi[2];
  f32x2 Mr3p; Mr3p.x = Mr[3]; Mr3p.y = Mr[3];
  f32x2 Mi3p; Mi3p.x = Mi[3]; Mi3p.y = Mi[3];

  // ---------- per-lane weights: hidden unit u = lane ----------
  // og/oi packed pairs (loop-invariant); od scalar
  f32x2 Wp[4], GOb;
  float WdP[4];
  #pragma unroll
  for (int m=0;m<4;m++){
    Wp[m].x = exw[(lane      )*4+m] * (-LOG2E);
    Wp[m].y = exw[(64  + lane)*4+m] * (-LOG2E);
    WdP[m]  = exw[(128 + lane)*4+m] * (2.f*LOG2E);
  }
  GOb.x = exb[lane]     * (-LOG2E);
  GOb.y = exb[64+lane]  * (-LOG2E);
  const float bdP = exb[128+lane] * (2.f*LOG2E);
  const float lw = nrw[lane], lb = nrb[lane];

  // WLc = Wh*lw centered by its mean (C1/64): y = fmaf(rstd, Sc, Yx')
  float WLc[4], C2[4];
  #pragma unroll
  for (int q=0;q<4;q++){
    const float whq = ew[q*192 + 128 + lane];
    const float wl  = whq * lw;
    const float c1  = red64(wl);
    WLc[q] = fmaf(-c1, 0.015625f, wl);
    C2[q]  = red64(whq * lb);
  }

  // Z signs under k = 4*m4 + r
  const float sg0  = (lane & 2) ? -1.f : 1.f;
  const float sg1  = (lane & 1) ? -1.f : 1.f;
  const float rsg2 = (r & 2)    ? -1.f : 1.f;
  const float rsg3 = (r & 1)    ? -1.f : 1.f;

  const float* yxp = yx + (size_t)e * T * 4;
  float* op = out + (size_t)e * T * 64 + lane;

  float Sc0=0.f, Sc1=0.f, Sc2=0.f, Sc3=0.f;
  float mu=0.f, rstd=0.f;
  float cst=0.f, h=0.f;

  float4 yA = *(const float4*)(yxp);
  yA.x -= C2[0]; yA.y -= C2[1]; yA.z -= C2[2]; yA.w -= C2[3];
  float4 yB = (T>1) ? *(const float4*)(yxp + 4) : yA;

#define STEP(TCUR, YBUF, PF)                                                      \
  {                                                                               \
    const int t_ = (TCUR);                                                        \
    const float y0 = fmaf(rstd, Sc0, YBUF.x);                                     \
    const float y1 = fmaf(rstd, Sc1, YBUF.y);                                     \
    const float y2 = fmaf(rstd, Sc2, YBUF.z);                                     \
    const float y3 = fmaf(rstd, Sc3, YBUF.w);                                     \
    if (PF){ YBUF = *(const float4*)(yxp + (size_t)(t_+2)*4); }                   \
    /* quad-specialized qubit encoding: this lane does qubit m4 only */           \
    const float ysel = (lane & 1) ? ((lane & 2) ? y3 : y1)                        \
                                  : ((lane & 2) ? y2 : y0);                       \
    float a_, br_, bi_;                                                           \
    {                                                                             \
      const float r2 = ysel*ysel;                                                 \
      const float c1 = frsq(fmaf(ysel,ysel,1.f));                                 \
      const float tt = (0.5f*ysel)*c1;                                            \
      a_  = fsqrt_(fmaxf(0.5f - tt, 0.f));                                        \
      const float bb = fsqrt_(0.5f + tt);                                         \
      const float cp = frsq(fmaf(r2,r2,1.f));                                     \
      br_ = bb*cp; bi_ = bb*(r2*cp);                                              \
    }                                                                             \
    float qa0,qa1,qa2,qa3,qr0,qr1,qr2,qr3,qi0,qi1,qi2,qi3;                        \
    quadbcast12_asm(a_,br_,bi_, qa0,qa1,qa2,qa3, qr0,qr1,qr2,qr3,                 \
                    qi0,qi1,qi2,qi3);                                             \
    /* A(c) = q0comp(lane&8) * q1comp(lane&4) — constant per lane */              \
    Cx sel0, sel1;                                                                \
    sel0.r = (lane & 8) ? qr0 : qa0;  sel0.i = (lane & 8) ? qi0 : 0.f;            \
    sel1.r = (lane & 4) ? qr1 : qa1;  sel1.i = (lane & 4) ? qi1 : 0.f;            \
    const Cx A = cmul(sel0, sel1);                                                \
    /* B pairs [re,im] (B0 real: lo-splat via op_sel in gmatvec_pk) */            \
    f32x2 B0p; B0p.x = qa2*qa3;  B0p.y = 0.f;                                     \
    f32x2 B1;  B1.x = qa2*qr3;   B1.y = qa2*qi3;                                  \
    f32x2 B2;  B2.x = qr2*qa3;   B2.y = qi2*qa3;                                  \
    f32x2 B3;  B3.x = fmaf(-qi2,qi3,qr2*qr3); B3.y = fmaf(qi2,qr3,qr2*qi3);       \
    /* G = sum_m M[k][4c+m] * B_m via packed complex fma (7 instrs) */            \
    f32x2 G;                                                                      \
    gmatvec_pk(G, M0p, Mr1p, Mi1p, Mr2p, Mi2p, Mr3p, Mi3p, B0p, B1, B2, B3);      \
    /* F-partial = A * G, then in-row chunk reduction */                          \
    float Fr = fmaf(-A.i, G.y, A.r*G.x);                                          \
    float Fi = fmaf( A.i, G.x, A.r*G.y);                                          \
    chunk2_asm(Fr, Fi);                                                           \
    const float p = fmaf(Fr,Fr, Fi*Fi);                                           \
    /* Z stage: fused interleaved asm */                                          \
    float Az = sg0*p, Bz = sg1*p, Cz = p, Dz, Ez;                                 \
    zred_asm(Az, Bz, Cz, Dz, Ez, rsg2, rsg3);                                     \
    const float q0 = rdl(Az, 63);                                                 \
    const float q1 = rdl(Bz, 63);                                                 \
    const float q2 = rdl(Dz, 63);                                                 \
    const float q3 = rdl(Ez, 63);                                                 \
    f32x2 Z01; Z01.x = y0+q0; Z01.y = y1+q1;                                      \
    f32x2 Z23; Z23.x = y2+q2; Z23.y = y3+q3;                                      \
    /* gates: og/oi packed (4 pk_fma), od scalar */                               \
    f32x2 GO;                                                                     \
    gates_pk(GO, Wp[0], Wp[1], Wp[2], Wp[3], Z01, Z23, GOb);                      \
    const float od = fmaf(WdP[3],Z23.y, fmaf(WdP[2],Z23.x,                        \
                     fmaf(WdP[1],Z01.y, fmaf(WdP[0],Z01.x, bdP))));               \
    const float g  = med3(frcp(1.f + ex2(GO.x)), 0.05f, 0.95f);                   \
    const float ig = frcp(1.f + ex2(GO.y));                                       \
    const float dt = fmaf(-2.f, frcp(1.f + ex2(od)), 1.f);                        \
    cst = fmaf(fmaf(-0.9f, g, 0.9f), cst, ig*dt);                                 \
    const float th = fmaf(-2.f, frcp(1.f + ex2((2.f*LOG2E)*cst)), 1.f);           \
    const float pre = g * th;                                                     \
    /* fused LN + centered next-entry reductions: six interleaved chains */       \
    float u1 = pre, u2 = pre*pre;                                                 \
    float w0p = WLc[0]*pre, w1p = WLc[1]*pre, w2p = WLc[2]*pre, w3p = WLc[3]*pre; \
    red64x6_asm(u1, u2, w0p, w1p, w2p, w3p);                                      \
    const float s1 = rdl(u1, 63);                                                 \
    const float s2 = rdl(u2, 63);                                                 \
    Sc0 = rdl(w0p, 63); Sc1 = rdl(w1p, 63);                                       \
    Sc2 = rdl(w2p, 63); Sc3 = rdl(w3p, 63);                                       \
    mu = s1 * (1.f/64.f);                                                         \
    const float var = fmaf(s2, 1.f/64.f, -mu*mu);                                 \
    rstd = frsq(var + 1e-5f);                                                     \
    h = fmaf((pre - mu)*rstd, lw, lb);                                            \
    op[(size_t)t_*64] = h;                                                        \
  }

  // hot loop unrolled x4 (T % 4 == 0, T >= 8); last 4 peeled (2 with PF, 2 without)
  int t = 0;
  for (; t < T-4; t += 4){
    STEP(t,   yA, 1);
    STEP(t+1, yB, 1);
    STEP(t+2, yA, 1);
    STEP(t+3, yB, 1);
  }
  STEP(t,   yA, 1);
  STEP(t+1, yB, 1);
  STEP(t+2, yA, 0);
  STEP(t+3, yB, 0);
#undef STEP

  // final hidden state h_T
  out[hToff + (size_t)e*64 + lane] = h;
}

extern "C" void kernel_launch(void* const* d_in, const int* in_sizes, int n_in,
                              void* d_out, int out_size, void* d_ws, size_t ws_size,
                              hipStream_t stream)
{
  const float* x   = (const float*)d_in[0];
  const float* fw  = (const float*)d_in[1];
  const float* ew  = (const float*)d_in[2];
  const float* eb  = (const float*)d_in[3];
  const float* exw = (const float*)d_in[4];
  const float* exb = (const float*)d_in[5];
  const float* vw  = (const float*)d_in[6];
  const float* nw  = (const float*)d_in[7];
  const float* nb  = (const float*)d_in[8];

  const long long BT = in_sizes[0] / 128;           // B*T
  const int B = (int)((long long)out_size/64 - BT); // out = B*T*64 + B*64
  const int T = (int)(BT / B);

  float* yxbuf = (float*)d_ws;                      // B*T*4 floats (2 MB)

  yx_pre<<<1024, 256, 0, stream>>>(x, fw, ew, eb, nb, yxbuf, BT);
  qssm64<<<B, 64, 0, stream>>>(ew, exw, exb, vw, nw, nb,
                               yxbuf, (float*)d_out, T, (long long)BT*64);
}

// Round 19
// 248.096 us; speedup vs baseline: 1.0071x; 1.0071x over previous
//
#include <hip/hip_runtime.h>

#define DEV static __device__ __forceinline__

struct Cx { float r, i; };
DEV Cx cmul(Cx a, Cx b){ Cx o; o.r = a.r*b.r - a.i*b.i; o.i = a.r*b.i + a.i*b.r; return o; }

// ---- builtin DPP helpers (preamble / yx_pre only) ----
template<int CTRL>
DEV float dppf(float x){
  int v = __builtin_amdgcn_update_dpp(0, __builtin_bit_cast(int, x), CTRL, 0xF, 0xF, true);
  return __builtin_bit_cast(float, v);
}
DEV float rdl(float v, int l){
  return __builtin_bit_cast(float, __builtin_amdgcn_readlane(__builtin_bit_cast(int, v), l));
}
DEV float red64(float v){           // preamble-only (builtin form, proven R12)
  v += dppf<0x111>(v); v += dppf<0x112>(v); v += dppf<0x114>(v); v += dppf<0x118>(v);
  v += dppf<0x142>(v); v += dppf<0x143>(v);
  return rdl(v, 63);
}
DEV float sx16(float v){ return __shfl_xor(v, 16); }
DEV float sx32(float v){ return __shfl_xor(v, 32); }
DEV float full64(float v){
  v += dppf<0xB1>(v); v += dppf<0x4E>(v); v += dppf<0x124>(v); v += dppf<0x128>(v);
  v += sx16(v); v += sx32(v);
  return v;
}

// ---- fused-DPP asm blocks (interleaved chains; proven R15/R16/R17) ----
#define DPPMODS " row_mask:0xf bank_mask:0xf bound_ctrl:0\n\t"
// six independent full-64 sums; result (total) lands in lane 63 of each
DEV void red64x6_asm(float &a, float &b, float &c, float &d, float &e, float &f){
  asm("s_nop 1\n\t"
      "v_add_f32_dpp %0, %0, %0 quad_perm:[1,0,3,2]" DPPMODS
      "v_add_f32_dpp %1, %1, %1 quad_perm:[1,0,3,2]" DPPMODS
      "v_add_f32_dpp %2, %2, %2 quad_perm:[1,0,3,2]" DPPMODS
      "v_add_f32_dpp %3, %3, %3 quad_perm:[1,0,3,2]" DPPMODS
      "v_add_f32_dpp %4, %4, %4 quad_perm:[1,0,3,2]" DPPMODS
      "v_add_f32_dpp %5, %5, %5 quad_perm:[1,0,3,2]" DPPMODS
      "v_add_f32_dpp %0, %0, %0 quad_perm:[2,3,0,1]" DPPMODS
      "v_add_f32_dpp %1, %1, %1 quad_perm:[2,3,0,1]" DPPMODS
      "v_add_f32_dpp %2, %2, %2 quad_perm:[2,3,0,1]" DPPMODS
      "v_add_f32_dpp %3, %3, %3 quad_perm:[2,3,0,1]" DPPMODS
      "v_add_f32_dpp %4, %4, %4 quad_perm:[2,3,0,1]" DPPMODS
      "v_add_f32_dpp %5, %5, %5 quad_perm:[2,3,0,1]" DPPMODS
      "v_add_f32_dpp %0, %0, %0 row_ror:4" DPPMODS
      "v_add_f32_dpp %1, %1, %1 row_ror:4" DPPMODS
      "v_add_f32_dpp %2, %2, %2 row_ror:4" DPPMODS
      "v_add_f32_dpp %3, %3, %3 row_ror:4" DPPMODS
      "v_add_f32_dpp %4, %4, %4 row_ror:4" DPPMODS
      "v_add_f32_dpp %5, %5, %5 row_ror:4" DPPMODS
      "v_add_f32_dpp %0, %0, %0 row_ror:8" DPPMODS
      "v_add_f32_dpp %1, %1, %1 row_ror:8" DPPMODS
      "v_add_f32_dpp %2, %2, %2 row_ror:8" DPPMODS
      "v_add_f32_dpp %3, %3, %3 row_ror:8" DPPMODS
      "v_add_f32_dpp %4, %4, %4 row_ror:8" DPPMODS
      "v_add_f32_dpp %5, %5, %5 row_ror:8" DPPMODS
      "v_add_f32_dpp %0, %0, %0 row_bcast:15" DPPMODS
      "v_add_f32_dpp %1, %1, %1 row_bcast:15" DPPMODS
      "v_add_f32_dpp %2, %2, %2 row_bcast:15" DPPMODS
      "v_add_f32_dpp %3, %3, %3 row_bcast:15" DPPMODS
      "v_add_f32_dpp %4, %4, %4 row_bcast:15" DPPMODS
      "v_add_f32_dpp %5, %5, %5 row_bcast:15" DPPMODS
      "v_add_f32_dpp %0, %0, %0 row_bcast:31" DPPMODS
      "v_add_f32_dpp %1, %1, %1 row_bcast:31" DPPMODS
      "v_add_f32_dpp %2, %2, %2 row_bcast:31" DPPMODS
      "v_add_f32_dpp %3, %3, %3 row_bcast:31" DPPMODS
      "v_add_f32_dpp %4, %4, %4 row_bcast:31" DPPMODS
      "v_add_f32_dpp %5, %5, %5 row_bcast:31" DPPMODS
      : "+v"(a), "+v"(b), "+v"(c), "+v"(d), "+v"(e), "+v"(f));
}
// Z-stage: A=sg0*p, B=sg1*p quad+row reduce; C=p quad reduce -> D=rsg2*C, E=rsg3*C row reduce
DEV void zred_asm(float &A, float &B, float &C, float &D, float &E,
                  float rsg2, float rsg3){
  asm("s_nop 1\n\t"
      "v_add_f32_dpp %0, %0, %0 quad_perm:[1,0,3,2]" DPPMODS
      "v_add_f32_dpp %1, %1, %1 quad_perm:[1,0,3,2]" DPPMODS
      "v_add_f32_dpp %2, %2, %2 quad_perm:[1,0,3,2]" DPPMODS
      "v_add_f32_dpp %0, %0, %0 quad_perm:[2,3,0,1]" DPPMODS
      "v_add_f32_dpp %1, %1, %1 quad_perm:[2,3,0,1]" DPPMODS
      "v_add_f32_dpp %2, %2, %2 quad_perm:[2,3,0,1]" DPPMODS
      "v_mul_f32 %3, %5, %2\n\t"
      "v_mul_f32 %4, %6, %2\n\t"
      "v_add_f32_dpp %0, %0, %0 row_bcast:15" DPPMODS
      "v_add_f32_dpp %1, %1, %1 row_bcast:15" DPPMODS
      "v_add_f32_dpp %3, %3, %3 row_bcast:15" DPPMODS
      "v_add_f32_dpp %4, %4, %4 row_bcast:15" DPPMODS
      "v_add_f32_dpp %0, %0, %0 row_bcast:31" DPPMODS
      "v_add_f32_dpp %1, %1, %1 row_bcast:31" DPPMODS
      "v_add_f32_dpp %3, %3, %3 row_bcast:31" DPPMODS
      "v_add_f32_dpp %4, %4, %4 row_bcast:31" DPPMODS
      : "+v"(A), "+v"(B), "+v"(C), "=&v"(D), "=&v"(E)
      : "v"(rsg2), "v"(rsg3));
}
// Fr/Fi in-row chunk sums (ror4 + ror8), two chains
DEV void chunk2_asm(float &F, float &G){
  asm("s_nop 1\n\t"
      "v_add_f32_dpp %0, %0, %0 row_ror:4" DPPMODS
      "v_add_f32_dpp %1, %1, %1 row_ror:4" DPPMODS
      "s_nop 0\n\t"
      "v_add_f32_dpp %0, %0, %0 row_ror:8" DPPMODS
      "v_add_f32_dpp %1, %1, %1 row_ror:8" DPPMODS
      : "+v"(F), "+v"(G));
}
// 12 quad broadcasts of (a, br, bi) -> per-qubit values in every lane
DEV void quadbcast12_asm(float a, float br, float bi,
  float &a0,float &a1,float &a2,float &a3,
  float &r0,float &r1,float &r2,float &r3,
  float &i0,float &i1,float &i2,float &i3){
  asm("s_nop 1\n\t"
      "v_mov_b32_dpp %0, %12 quad_perm:[0,0,0,0]" DPPMODS
      "v_mov_b32_dpp %1, %12 quad_perm:[1,1,1,1]" DPPMODS
      "v_mov_b32_dpp %2, %12 quad_perm:[2,2,2,2]" DPPMODS
      "v_mov_b32_dpp %3, %12 quad_perm:[3,3,3,3]" DPPMODS
      "v_mov_b32_dpp %4, %13 quad_perm:[0,0,0,0]" DPPMODS
      "v_mov_b32_dpp %5, %13 quad_perm:[1,1,1,1]" DPPMODS
      "v_mov_b32_dpp %6, %13 quad_perm:[2,2,2,2]" DPPMODS
      "v_mov_b32_dpp %7, %13 quad_perm:[3,3,3,3]" DPPMODS
      "v_mov_b32_dpp %8, %14 quad_perm:[0,0,0,0]" DPPMODS
      "v_mov_b32_dpp %9, %14 quad_perm:[1,1,1,1]" DPPMODS
      "v_mov_b32_dpp %10, %14 quad_perm:[2,2,2,2]" DPPMODS
      "v_mov_b32_dpp %11, %14 quad_perm:[3,3,3,3]" DPPMODS
      : "=&v"(a0), "=&v"(a1), "=&v"(a2), "=&v"(a3),
        "=&v"(r0), "=&v"(r1), "=&v"(r2), "=&v"(r3),
        "=&v"(i0), "=&v"(i1), "=&v"(i2), "=&v"(i3)
      : "v"(a), "v"(br), "v"(bi));
}

DEV float fexp(float x){ return __builtin_amdgcn_exp2f(x * 1.44269504088896341f); }
DEV float ex2(float x){ return __builtin_amdgcn_exp2f(x); }
DEV float frcp(float x){ return __builtin_amdgcn_rcpf(x); }
DEV float frsq(float x){ return __builtin_amdgcn_rsqf(x); }
DEV float fsqrt_(float x){ return __builtin_amdgcn_sqrtf(x); }
DEV float med3(float x, float lo, float hi){ return __builtin_amdgcn_fmed3f(x, lo, hi); }

#define LOG2E 1.44269504088896341f

// =================== Kernel 1: Yx precompute + C2 bias fold [R17-proven] ===================
__global__ void yx_pre(const float* __restrict__ x, const float* __restrict__ fw,
                       const float* __restrict__ ew, const float* __restrict__ eb,
                       const float* __restrict__ nrb,
                       float* __restrict__ yx, long long nrows)
{
  const int lane = threadIdx.x & 63;
  const long long wid = (long long)blockIdx.x * (blockDim.x >> 6) + (threadIdx.x >> 6);
  const long long nw  = (long long)gridDim.x * (blockDim.x >> 6);
  float w0_,w1_,w2_,w3_,v0_,v1_,v2_,v3_;
  {
    const float f0 = fexp(fw[2*lane]), f1 = fexp(fw[2*lane+1]);
    w0_ = ew[0*192+2*lane]*f0; v0_ = ew[0*192+2*lane+1]*f1;
    w1_ = ew[1*192+2*lane]*f0; v1_ = ew[1*192+2*lane+1]*f1;
    w2_ = ew[2*192+2*lane]*f0; v2_ = ew[2*192+2*lane+1]*f1;
    w3_ = ew[3*192+2*lane]*f0; v3_ = ew[3*192+2*lane+1]*f1;
  }
  // C2 fold: bias' = eb + C2
  const float lb = nrb[lane];
  float b0,b1,b2,b3;
  {
    b0 = eb[0] + full64(ew[0*192+128+lane]*lb);
    b1 = eb[1] + full64(ew[1*192+128+lane]*lb);
    b2 = eb[2] + full64(ew[2*192+128+lane]*lb);
    b3 = eb[3] + full64(ew[3*192+128+lane]*lb);
  }
  for (long long row = wid; row < nrows; row += nw){
    const float2 xv = *(const float2*)(x + row*128 + 2*lane);
    float a0 = fmaf(v0_,xv.y, w0_*xv.x);
    float a1 = fmaf(v1_,xv.y, w1_*xv.x);
    float a2 = fmaf(v2_,xv.y, w2_*xv.x);
    float a3 = fmaf(v3_,xv.y, w3_*xv.x);
    a0 = full64(a0); a1 = full64(a1); a2 = full64(a2); a3 = full64(a3);
    if (lane == 0){
      float4 o; o.x=a0+b0; o.y=a1+b1; o.z=a2+b2; o.w=a3+b3;
      *(float4*)(yx + row*4) = o;
    }
  }
}

// =================== Kernel 2: recurrence, 64 lanes per element ===================
// R19 = exact revert to R17 (best: 248.5 us). R18's packed-f32 was null-to-negative
// (chain-bound at the margin). This structure is at its latency/issue floor.
__global__ void __launch_bounds__(64) qssm64(
  const float* __restrict__ ew, const float* __restrict__ exw,
  const float* __restrict__ exb,const float* __restrict__ vw,
  const float* __restrict__ nrw,const float* __restrict__ nrb,
  const float* __restrict__ yx, float* __restrict__ out,
  int T, long long hToff)
{
  const int lane = threadIdx.x;      // 0..63
  const int e    = blockIdx.x;       // batch element
  const int r    = lane >> 4;        // row
  const int m4   = lane & 3;         // quad position (qubit this lane encodes)
  const int k    = 4*m4 + r;         // amplitude this lane owns (F-matvec)
  const int c    = (lane >> 2) & 3;  // j-chunk this lane sums

  // ---------- build fixed circuit matrix M (16x16 complex) once [R4-verbatim] ----------
  __shared__ float MrS[16][16];
  __shared__ float MiS[16][16];
  if (lane < 16){
    const int j = lane;
    float w2[2][3][4];
    #pragma unroll
    for (int ll=0;ll<2;ll++)
      #pragma unroll
      for (int g=0;g<3;g++)
        #pragma unroll
        for (int i=0;i<4;i++) w2[ll][g][i] = 0.5f * vw[(ll*3+g)*4+i];
    float sr[16], si[16];
    #pragma unroll
    for (int n=0;n<16;n++){ sr[n] = (n==j)?1.f:0.f; si[n]=0.f; }
    #pragma unroll
    for (int ll=0;ll<2;ll++){
      #pragma unroll
      for (int cq=0;cq<4;cq++){
        const int tq=(cq+1)&3, mc=1<<(3-cq), mt=1<<(3-tq);
        #pragma unroll
        for (int n=0;n<16;n++){
          if ((n&mc) && !(n&mt)){
            const int n1 = n|mt;
            float tr=sr[n], ti=si[n];
            sr[n]=sr[n1]; si[n]=si[n1];
            sr[n1]=tr;    si[n1]=ti;
          }
        }
      }
      #pragma unroll
      for (int i=0;i<4;i++){
        const int m=1<<(3-i);
        const float cx=cosf(w2[ll][0][i]), sxx=sinf(w2[ll][0][i]);
        const float cy=cosf(w2[ll][1][i]), sy=sinf(w2[ll][1][i]);
        const float cz=cosf(w2[ll][2][i]), sz=sinf(w2[ll][2][i]);
        #pragma unroll
        for (int n=0;n<16;n++){
          if (!(n&m)){
            const int n1=n|m;
            float a0r=sr[n], a0i=si[n], a1r=sr[n1], a1i=si[n1];
            float b0r = cx*a0r + sxx*a1i, b0i = cx*a0i - sxx*a1r;
            float b1r = sxx*a0i + cx*a1r, b1i = -sxx*a0r + cx*a1i;
            float c0r = cy*b0r - sy*b1r, c0i = cy*b0i - sy*b1i;
            float c1r = sy*b0r + cy*b1r, c1i = sy*b0i + cy*b1i;
            sr[n]  = cz*c0r + sz*c0i;  si[n]  = cz*c0i - sz*c0r;
            sr[n1] = cz*c1r - sz*c1i;  si[n1] = cz*c1i + sz*c1r;
          }
        }
      }
    }
    #pragma unroll
    for (int n=0;n<16;n++){ MrS[n][j]=sr[n]; MiS[n][j]=si[n]; }
  }
  __syncthreads();

  // M fragment: row k, columns 4c..4c+3
  float Mr[4], Mi[4];
  #pragma unroll
  for (int m=0;m<4;m++){ Mr[m]=MrS[k][4*c+m]; Mi[m]=MiS[k][4*c+m]; }

  // ---------- per-lane weights: hidden unit u = lane [R12-verbatim] ----------
  float WgP[4], WiP[4], WdP[4];
  #pragma unroll
  for (int m=0;m<4;m++){
    WgP[m] = exw[(lane      )*4+m] * (-LOG2E);
    WiP[m] = exw[(64  + lane)*4+m] * (-LOG2E);
    WdP[m] = exw[(128 + lane)*4+m] * (2.f*LOG2E);
  }
  const float bgP = exb[lane]     * (-LOG2E);
  const float biP = exb[64+lane]  * (-LOG2E);
  const float bdP = exb[128+lane] * (2.f*LOG2E);
  const float lw = nrw[lane], lb = nrb[lane];

  // WLc = Wh*lw centered by its mean (C1/64): y = fmaf(rstd, Sc, Yx')
  float WLc[4], C2[4];
  #pragma unroll
  for (int q=0;q<4;q++){
    const float whq = ew[q*192 + 128 + lane];
    const float wl  = whq * lw;
    const float c1  = red64(wl);
    WLc[q] = fmaf(-c1, 0.015625f, wl);
    C2[q]  = red64(whq * lb);
  }

  // Z signs under k = 4*m4 + r:  k&8 -> m4&2, k&4 -> m4&1, k&2 -> r&2, k&1 -> r&1
  const float sg0  = (lane & 2) ? -1.f : 1.f;   // in-quad
  const float sg1  = (lane & 1) ? -1.f : 1.f;   // in-quad
  const float rsg2 = (r & 2)    ? -1.f : 1.f;   // row sign
  const float rsg3 = (r & 1)    ? -1.f : 1.f;   // row sign

  const float* yxp = yx + (size_t)e * T * 4;
  float* op = out + (size_t)e * T * 64 + lane;

  float Sc0=0.f, Sc1=0.f, Sc2=0.f, Sc3=0.f;
  float mu=0.f, rstd=0.f;
  float cst=0.f, h=0.f;

  float4 yA = *(const float4*)(yxp);
  // t=0 correction: yx carries +C2, but h(-1)=0 => subtract C2 for step 0
  yA.x -= C2[0]; yA.y -= C2[1]; yA.z -= C2[2]; yA.w -= C2[3];
  float4 yB = (T>1) ? *(const float4*)(yxp + 4) : yA;

#define STEP(TCUR, YBUF, PF)                                                      \
  {                                                                               \
    const int t_ = (TCUR);                                                        \
    const float y0 = fmaf(rstd, Sc0, YBUF.x);                                     \
    const float y1 = fmaf(rstd, Sc1, YBUF.y);                                     \
    const float y2 = fmaf(rstd, Sc2, YBUF.z);                                     \
    const float y3 = fmaf(rstd, Sc3, YBUF.w);                                     \
    if (PF){ YBUF = *(const float4*)(yxp + (size_t)(t_+2)*4); }                   \
    /* quad-specialized qubit encoding: this lane does qubit m4 only */           \
    const float ysel = (lane & 1) ? ((lane & 2) ? y3 : y1)                        \
                                  : ((lane & 2) ? y2 : y0);                       \
    float a_, br_, bi_;                                                           \
    {                                                                             \
      const float r2 = ysel*ysel;                                                 \
      const float c1 = frsq(fmaf(ysel,ysel,1.f));                                 \
      const float tt = (0.5f*ysel)*c1;                                            \
      a_  = fsqrt_(fmaxf(0.5f - tt, 0.f));                                        \
      const float bb = fsqrt_(0.5f + tt);                                         \
      const float cp = frsq(fmaf(r2,r2,1.f));                                     \
      br_ = bb*cp; bi_ = bb*(r2*cp);                                              \
    }                                                                             \
    /* distribute all 4 qubits' (a,br,bi) via fused quad-broadcast movs */        \
    float qa0,qa1,qa2,qa3,qr0,qr1,qr2,qr3,qi0,qi1,qi2,qi3;                        \
    quadbcast12_asm(a_,br_,bi_, qa0,qa1,qa2,qa3, qr0,qr1,qr2,qr3,                 \
                    qi0,qi1,qi2,qi3);                                             \
    /* A(c) = q0comp(lane&8) * q1comp(lane&4) — constant per lane */              \
    Cx sel0, sel1;                                                                \
    sel0.r = (lane & 8) ? qr0 : qa0;  sel0.i = (lane & 8) ? qi0 : 0.f;            \
    sel1.r = (lane & 4) ? qr1 : qa1;  sel1.i = (lane & 4) ? qi1 : 0.f;            \
    const Cx A = cmul(sel0, sel1);                                                \
    /* B components (B0 real) */                                                  \
    const float B0r = qa2*qa3;                                                    \
    const float B1r = qa2*qr3, B1i = qa2*qi3;                                     \
    const float B2r = qr2*qa3, B2i = qi2*qa3;                                     \
    const float B3r = fmaf(-qi2,qi3,qr2*qr3), B3i = fmaf(qi2,qr3,qr2*qi3);        \
    /* G = sum_m M[k][4c+m] * B_m  (14 fma) */                                    \
    float Gr = Mr[0]*B0r;                                                         \
    float Gi = Mi[0]*B0r;                                                         \
    Gr = fmaf(Mr[1],B1r,Gr); Gr = fmaf(-Mi[1],B1i,Gr);                            \
    Gi = fmaf(Mr[1],B1i,Gi); Gi = fmaf( Mi[1],B1r,Gi);                            \
    Gr = fmaf(Mr[2],B2r,Gr); Gr = fmaf(-Mi[2],B2i,Gr);                            \
    Gi = fmaf(Mr[2],B2i,Gi); Gi = fmaf( Mi[2],B2r,Gi);                            \
    Gr = fmaf(Mr[3],B3r,Gr); Gr = fmaf(-Mi[3],B3i,Gr);                            \
    Gi = fmaf(Mr[3],B3i,Gi); Gi = fmaf( Mi[3],B3r,Gi);                            \
    /* F-partial = A * G, then in-row chunk reduction */                          \
    float Fr = fmaf(-A.i, Gi, A.r*Gr);                                            \
    float Fi = fmaf( A.i, Gr, A.r*Gi);                                            \
    chunk2_asm(Fr, Fi);                                                           \
    const float p = fmaf(Fr,Fr, Fi*Fi);                                           \
    /* Z stage: fused interleaved asm (quad sums + row bcast cascades) */         \
    float Az = sg0*p, Bz = sg1*p, Cz = p, Dz, Ez;                                 \
    zred_asm(Az, Bz, Cz, Dz, Ez, rsg2, rsg3);                                     \
    const float q0 = rdl(Az, 63);                                                 \
    const float q1 = rdl(Bz, 63);                                                 \
    const float q2 = rdl(Dz, 63);                                                 \
    const float q3 = rdl(Ez, 63);                                                 \
    const float z0=y0+q0, z1=y1+q1, z2=y2+q2, z3=y3+q3;                           \
    /* gates (exp2-prescaled weights) */                                          \
    const float og = fmaf(WgP[3],z3, fmaf(WgP[2],z2, fmaf(WgP[1],z1, fmaf(WgP[0],z0, bgP)))); \
    const float oi = fmaf(WiP[3],z3, fmaf(WiP[2],z2, fmaf(WiP[1],z1, fmaf(WiP[0],z0, biP)))); \
    const float od = fmaf(WdP[3],z3, fmaf(WdP[2],z2, fmaf(WdP[1],z1, fmaf(WdP[0],z0, bdP)))); \
    const float g  = med3(frcp(1.f + ex2(og)), 0.05f, 0.95f);                     \
    const float ig = frcp(1.f + ex2(oi));                                         \
    const float dt = fmaf(-2.f, frcp(1.f + ex2(od)), 1.f);                        \
    cst = fmaf(fmaf(-0.9f, g, 0.9f), cst, ig*dt);                                 \
    const float th = fmaf(-2.f, frcp(1.f + ex2((2.f*LOG2E)*cst)), 1.f);           \
    const float pre = g * th;                                                     \
    /* fused LN + centered next-entry reductions: six interleaved chains */       \
    float u1 = pre, u2 = pre*pre;                                                 \
    float w0p = WLc[0]*pre, w1p = WLc[1]*pre, w2p = WLc[2]*pre, w3p = WLc[3]*pre; \
    red64x6_asm(u1, u2, w0p, w1p, w2p, w3p);                                      \
    const float s1 = rdl(u1, 63);                                                 \
    const float s2 = rdl(u2, 63);                                                 \
    Sc0 = rdl(w0p, 63); Sc1 = rdl(w1p, 63);                                       \
    Sc2 = rdl(w2p, 63); Sc3 = rdl(w3p, 63);                                       \
    mu = s1 * (1.f/64.f);                                                         \
    const float var = fmaf(s2, 1.f/64.f, -mu*mu);                                 \
    rstd = frsq(var + 1e-5f);                                                     \
    h = fmaf((pre - mu)*rstd, lw, lb);                                            \
    op[(size_t)t_*64] = h;                                                        \
  }

  // hot loop: unconditional prefetch (t+2 <= T-1 guaranteed); last 2 peeled
  int t = 0;
  for (; t < T-2; t += 2){
    STEP(t,   yA, 1);
    STEP(t+1, yB, 1);
  }
  STEP(t,   yA, 0);
  STEP(t+1, yB, 0);
#undef STEP

  // final hidden state h_T
  out[hToff + (size_t)e*64 + lane] = h;
}

extern "C" void kernel_launch(void* const* d_in, const int* in_sizes, int n_in,
                              void* d_out, int out_size, void* d_ws, size_t ws_size,
                              hipStream_t stream)
{
  const float* x   = (const float*)d_in[0];
  const float* fw  = (const float*)d_in[1];
  const float* ew  = (const float*)d_in[2];
  const float* eb  = (const float*)d_in[3];
  const float* exw = (const float*)d_in[4];
  const float* exb = (const float*)d_in[5];
  const float* vw  = (const float*)d_in[6];
  const float* nw  = (const float*)d_in[7];
  const float* nb  = (const float*)d_in[8];

  const long long BT = in_sizes[0] / 128;           // B*T
  const int B = (int)((long long)out_size/64 - BT); // out = B*T*64 + B*64
  const int T = (int)(BT / B);

  float* yxbuf = (float*)d_ws;                      // B*T*4 floats (2 MB)

  yx_pre<<<1024, 256, 0, stream>>>(x, fw, ew, eb, nb, yxbuf, BT);
  qssm64<<<B, 64, 0, stream>>>(ew, exw, exb, vw, nw, nb,
                               yxbuf, (float*)d_out, T, (long long)BT*64);
}